// Round 2
// baseline (2067.962 us; speedup 1.0000x reference)
//
#include <hip/hip_runtime.h>
#include <hip/hip_bf16.h>
#include <math.h>

#define B_   2
#define S_   2048
#define D_   1024
#define H_   16
#define HD_  64
#define WIN_ 256

// ---------------------------------------------------------------------------
// RoPE cos/sin table: [S][32] each. Angle computed with f32 rounding (matches
// jnp f32 outer product), trig evaluated in f64 for accuracy.
// ---------------------------------------------------------------------------
__global__ void rope_table_kernel(float* __restrict__ cosT, float* __restrict__ sinT)
{
    int idx = blockIdx.x * 256 + threadIdx.x;
    if (idx >= S_ * 32) return;
    int s = idx >> 5;
    int i = idx & 31;
    float invf = 1.0f / powf(10000.0f, (float)(2 * i) / 64.0f);
    float ang  = (float)s * invf;                 // f32 rounding like reference
    double a = (double)ang;
    cosT[idx] = (float)cos(a);
    sinT[idx] = (float)sin(a);
}

// ---------------------------------------------------------------------------
// Fused QKV projection + RoPE epilogue: Y = rope(X @ W^T + b) for Q,K; V plain.
// X: [4096,1024] f32.  Combined N = 3072.  Tiles 128x128, BK=16, 256 thr,
// 8x8 outputs/thread. Epilogue scatters to [B,H,S,64].
// RoPE pair (d, d^32) lives at lane tx^8 -> __shfl_xor(.., 8).
// ---------------------------------------------------------------------------
__global__ __launch_bounds__(256)
void qkv_gemm_kernel(const float* __restrict__ X,
                     const float* __restrict__ Wq, const float* __restrict__ Wk,
                     const float* __restrict__ Wv,
                     const float* __restrict__ bq, const float* __restrict__ bk,
                     const float* __restrict__ bv,
                     const float* __restrict__ cosT, const float* __restrict__ sinT,
                     float* __restrict__ Qo, float* __restrict__ Ko, float* __restrict__ Vo)
{
    __shared__ float As[16][132];   // [k][m]
    __shared__ float Bs[16][132];   // [k][n]

    const int tid = threadIdx.x;
    const int ty = tid >> 4, tx = tid & 15;
    const int m0  = blockIdx.y * 128;
    const int nc0 = blockIdx.x * 128;
    const int wsel  = nc0 >> 10;          // which of Wq/Wk/Wv
    const int n_in0 = nc0 & 1023;

    const float* W  = (wsel == 0) ? Wq : (wsel == 1) ? Wk : Wv;
    const float* bi = (wsel == 0) ? bq : (wsel == 1) ? bk : bv;
    float* Out      = (wsel == 0) ? Qo : (wsel == 1) ? Ko : Vo;

    float acc[2][2][4][4];
#pragma unroll
    for (int a = 0; a < 2; ++a)
#pragma unroll
        for (int c = 0; c < 2; ++c)
#pragma unroll
            for (int i = 0; i < 4; ++i)
#pragma unroll
                for (int j = 0; j < 4; ++j) acc[a][c][i][j] = 0.f;

    const int lrow = tid >> 2;   // 0..63
    const int lkq  = tid & 3;    // 0..3

    for (int k0 = 0; k0 < D_; k0 += 16) {
#pragma unroll
        for (int r = 0; r < 2; ++r) {
            const int row = lrow + r * 64;
            float4 av = *(const float4*)&X[(size_t)(m0 + row) * D_ + k0 + lkq * 4];
            float4 wv = *(const float4*)&W[(size_t)(n_in0 + row) * D_ + k0 + lkq * 4];
            As[lkq * 4 + 0][row] = av.x; As[lkq * 4 + 1][row] = av.y;
            As[lkq * 4 + 2][row] = av.z; As[lkq * 4 + 3][row] = av.w;
            Bs[lkq * 4 + 0][row] = wv.x; Bs[lkq * 4 + 1][row] = wv.y;
            Bs[lkq * 4 + 2][row] = wv.z; Bs[lkq * 4 + 3][row] = wv.w;
        }
        __syncthreads();

#pragma unroll
        for (int k = 0; k < 16; ++k) {
            float4 a0 = *(const float4*)&As[k][ty * 4];
            float4 a1 = *(const float4*)&As[k][64 + ty * 4];
            float4 b0 = *(const float4*)&Bs[k][tx * 4];
            float4 b1 = *(const float4*)&Bs[k][64 + tx * 4];
            float ar[2][4] = {{a0.x, a0.y, a0.z, a0.w}, {a1.x, a1.y, a1.z, a1.w}};
            float br[2][4] = {{b0.x, b0.y, b0.z, b0.w}, {b1.x, b1.y, b1.z, b1.w}};
#pragma unroll
            for (int ra = 0; ra < 2; ++ra)
#pragma unroll
                for (int rb = 0; rb < 2; ++rb)
#pragma unroll
                    for (int i = 0; i < 4; ++i)
#pragma unroll
                        for (int j = 0; j < 4; ++j)
                            acc[ra][rb][i][j] = fmaf(ar[ra][i], br[rb][j], acc[ra][rb][i][j]);
        }
        __syncthreads();
    }

    const int b = m0 >> 11;
    const bool doRope = (wsel < 2);
    const float sgn = (tx & 8) ? 1.f : -1.f;     // d>=32 : +pair*sin, d<32 : -pair*sin

#pragma unroll
    for (int ra = 0; ra < 2; ++ra)
#pragma unroll
        for (int i = 0; i < 4; ++i) {
            const int m = m0 + ra * 64 + ty * 4 + i;
            const int s = m & (S_ - 1);
            float4 c4 = make_float4(1.f, 1.f, 1.f, 1.f);
            float4 s4 = make_float4(0.f, 0.f, 0.f, 0.f);
            if (doRope) {
                c4 = *(const float4*)&cosT[s * 32 + (tx & 7) * 4];
                s4 = *(const float4*)&sinT[s * 32 + (tx & 7) * 4];
            }
#pragma unroll
            for (int rb = 0; rb < 2; ++rb) {
                const int n_in = n_in0 + rb * 64 + tx * 4;
                const int h = n_in >> 6;
                const int d = n_in & 63;
                float4 v;
                v.x = acc[ra][rb][i][0] + bi[n_in + 0];
                v.y = acc[ra][rb][i][1] + bi[n_in + 1];
                v.z = acc[ra][rb][i][2] + bi[n_in + 2];
                v.w = acc[ra][rb][i][3] + bi[n_in + 3];
                if (doRope) {
                    float px = __shfl_xor(v.x, 8, 64);
                    float py = __shfl_xor(v.y, 8, 64);
                    float pz = __shfl_xor(v.z, 8, 64);
                    float pw = __shfl_xor(v.w, 8, 64);
                    v.x = fmaf(v.x, c4.x, sgn * px * s4.x);
                    v.y = fmaf(v.y, c4.y, sgn * py * s4.y);
                    v.z = fmaf(v.z, c4.z, sgn * pz * s4.z);
                    v.w = fmaf(v.w, c4.w, sgn * pw * s4.w);
                }
                *(float4*)&Out[(((size_t)b * H_ + h) * S_ + s) * HD_ + d] = v;
            }
        }
}

// ---------------------------------------------------------------------------
// Sliding-window attention, flash-style online softmax.
// Block: one (b,h) x 64 query rows. 256 thr; thread (ty,tx) owns rows
// ty*4+i and INTERLEAVED key cols j = tx + 16*c  (c=0..3) of the 64x64 tile.
// Interleaving makes K-fragment reads stride-1 in rows -> conflict-free
// with pitch 68. sacc is reused as P (no separate p_ array). Score scale 8
// is folded into Qs at staging. Ks LDS is reused for P after a barrier.
// ---------------------------------------------------------------------------
__global__ __launch_bounds__(256, 3)
void attn_kernel(const float* __restrict__ Q, const float* __restrict__ K,
                 const float* __restrict__ V, const int* __restrict__ amask,
                 float* __restrict__ out)
{
    __shared__ float Qs[64][68];
    __shared__ float Ks[64][68];   // K tile, then P tile
    __shared__ float Vs[64][68];

    const int tid = threadIdx.x;
    const int ty = tid >> 4, tx = tid & 15;
    const int bh = blockIdx.x;
    const int b  = bh >> 4;
    const int i0 = blockIdx.y * 64;

    const float* Qb = Q + (size_t)bh * S_ * HD_;
    const float* Kb = K + (size_t)bh * S_ * HD_;
    const float* Vb = V + (size_t)bh * S_ * HD_;

#pragma unroll
    for (int r = 0; r < 4; ++r) {
        const int qi = tid + r * 256;
        const int row = qi >> 4, q4 = qi & 15;
        float4 qv = *(const float4*)&Qb[(size_t)(i0 + row) * HD_ + q4 * 4];
        qv.x *= 8.f; qv.y *= 8.f; qv.z *= 8.f; qv.w *= 8.f;   // fold score scale
        *(float4*)&Qs[row][q4 * 4] = qv;
    }

    float m_[4], l_[4], O_[4][4];
#pragma unroll
    for (int i = 0; i < 4; ++i) {
        m_[i] = -3.0e38f; l_[i] = 0.f;
#pragma unroll
        for (int j = 0; j < 4; ++j) O_[i][j] = 0.f;
    }

    const int jlo   = (i0 - WIN_ > 0) ? (i0 - WIN_) : 0;
    const int jhiex = (i0 + 64 + WIN_ < S_) ? (i0 + 64 + WIN_) : S_;

    for (int jt = jlo; jt < jhiex; jt += 64) {
        __syncthreads();
#pragma unroll
        for (int r = 0; r < 4; ++r) {
            const int qi = tid + r * 256;
            const int row = qi >> 4, q4 = qi & 15;
            *(float4*)&Ks[row][q4 * 4] = *(const float4*)&Kb[(size_t)(jt + row) * HD_ + q4 * 4];
            *(float4*)&Vs[row][q4 * 4] = *(const float4*)&Vb[(size_t)(jt + row) * HD_ + q4 * 4];
        }
        __syncthreads();

        // ---- S = Q @ K^T (interleaved cols: c -> key row tx + 16c) ----
        float sacc[4][4];
#pragma unroll
        for (int i = 0; i < 4; ++i)
#pragma unroll
            for (int c = 0; c < 4; ++c) sacc[i][c] = 0.f;

#pragma unroll
        for (int d4 = 0; d4 < 16; ++d4) {
            float4 k0 = *(const float4*)&Ks[tx +  0][d4 * 4];
            float4 k1 = *(const float4*)&Ks[tx + 16][d4 * 4];
            float4 k2 = *(const float4*)&Ks[tx + 32][d4 * 4];
            float4 k3 = *(const float4*)&Ks[tx + 48][d4 * 4];
#pragma unroll
            for (int i = 0; i < 4; ++i) {
                float4 q = *(const float4*)&Qs[ty * 4 + i][d4 * 4];
                sacc[i][0] = fmaf(q.x, k0.x, fmaf(q.y, k0.y, fmaf(q.z, k0.z, fmaf(q.w, k0.w, sacc[i][0]))));
                sacc[i][1] = fmaf(q.x, k1.x, fmaf(q.y, k1.y, fmaf(q.z, k1.z, fmaf(q.w, k1.w, sacc[i][1]))));
                sacc[i][2] = fmaf(q.x, k2.x, fmaf(q.y, k2.y, fmaf(q.z, k2.z, fmaf(q.w, k2.w, sacc[i][2]))));
                sacc[i][3] = fmaf(q.x, k3.x, fmaf(q.y, k3.y, fmaf(q.z, k3.z, fmaf(q.w, k3.w, sacc[i][3]))));
            }
        }

        // ---- online softmax (sacc becomes P in place) ----
        const bool fullTile = (jt - i0 >= -192) && (jt - i0 <= 192);
        bool kall[4];
#pragma unroll
        for (int c = 0; c < 4; ++c)
            kall[c] = (amask[b * S_ + jt + tx + 16 * c] > 0);

#pragma unroll
        for (int i = 0; i < 4; ++i) {
            const int qrow = i0 + ty * 4 + i;
            float rowm = -3.0e38f;
#pragma unroll
            for (int c = 0; c < 4; ++c) {
                const int jj = jt + tx + 16 * c;
                const bool allow = kall[c] && (fullTile || ((jj >= qrow - WIN_) && (jj <= qrow + WIN_)));
                const float sv = allow ? sacc[i][c] : -3.0e38f;
                sacc[i][c] = sv;
                rowm = fmaxf(rowm, sv);
            }
#pragma unroll
            for (int sh = 8; sh >= 1; sh >>= 1)
                rowm = fmaxf(rowm, __shfl_xor(rowm, sh, 64));
            const float mnew = fmaxf(m_[i], rowm);
            const float corr = __expf(m_[i] - mnew);
            float rs = 0.f;
#pragma unroll
            for (int c = 0; c < 4; ++c) {
                const float pv = (sacc[i][c] > -1.0e37f) ? __expf(sacc[i][c] - mnew) : 0.f;
                sacc[i][c] = pv;
                rs += pv;
            }
#pragma unroll
            for (int sh = 8; sh >= 1; sh >>= 1)
                rs += __shfl_xor(rs, sh, 64);
            l_[i] = l_[i] * corr + rs;
            m_[i] = mnew;
#pragma unroll
            for (int c = 0; c < 4; ++c) O_[i][c] *= corr;
        }

        __syncthreads();   // K reads done; Ks becomes P
#pragma unroll
        for (int i = 0; i < 4; ++i)
#pragma unroll
            for (int c = 0; c < 4; ++c)
                Ks[ty * 4 + i][tx + 16 * c] = sacc[i][c];
        __syncthreads();

        // ---- O += P @ V ----
#pragma unroll
        for (int c4 = 0; c4 < 16; ++c4) {
            float4 v0 = *(const float4*)&Vs[c4 * 4 + 0][tx * 4];
            float4 v1 = *(const float4*)&Vs[c4 * 4 + 1][tx * 4];
            float4 v2 = *(const float4*)&Vs[c4 * 4 + 2][tx * 4];
            float4 v3 = *(const float4*)&Vs[c4 * 4 + 3][tx * 4];
#pragma unroll
            for (int i = 0; i < 4; ++i) {
                float4 pa = *(const float4*)&Ks[ty * 4 + i][c4 * 4];
                O_[i][0] = fmaf(pa.x, v0.x, fmaf(pa.y, v1.x, fmaf(pa.z, v2.x, fmaf(pa.w, v3.x, O_[i][0]))));
                O_[i][1] = fmaf(pa.x, v0.y, fmaf(pa.y, v1.y, fmaf(pa.z, v2.y, fmaf(pa.w, v3.y, O_[i][1]))));
                O_[i][2] = fmaf(pa.x, v0.z, fmaf(pa.y, v1.z, fmaf(pa.z, v2.z, fmaf(pa.w, v3.z, O_[i][2]))));
                O_[i][3] = fmaf(pa.x, v0.w, fmaf(pa.y, v1.w, fmaf(pa.z, v2.w, fmaf(pa.w, v3.w, O_[i][3]))));
            }
        }
    }

    // ---- epilogue: normalize, query-mask, write [B,S,D] ----
    const int h = bh & 15;
#pragma unroll
    for (int i = 0; i < 4; ++i) {
        const int qrow = i0 + ty * 4 + i;
        const float rl = (l_[i] > 0.f) ? (1.0f / l_[i]) : 0.f;
        const float qm = (amask[b * S_ + qrow] > 0) ? 1.f : 0.f;
        const float f = rl * qm;
        float4 v;
        v.x = O_[i][0] * f; v.y = O_[i][1] * f;
        v.z = O_[i][2] * f; v.w = O_[i][3] * f;
        *(float4*)&out[((size_t)b * S_ + qrow) * D_ + h * HD_ + tx * 4] = v;
    }
}

// ---------------------------------------------------------------------------
extern "C" void kernel_launch(void* const* d_in, const int* in_sizes, int n_in,
                              void* d_out, int out_size, void* d_ws, size_t ws_size,
                              hipStream_t stream)
{
    const float* X  = (const float*)d_in[0];
    const int*   am = (const int*)d_in[1];
    const float* Wq = (const float*)d_in[2];
    const float* bq = (const float*)d_in[3];
    const float* Wk = (const float*)d_in[4];
    const float* bk = (const float*)d_in[5];
    const float* Wv = (const float*)d_in[6];
    const float* bv = (const float*)d_in[7];
    float* out = (float*)d_out;

    float* ws = (float*)d_ws;
    const size_t nqkv = (size_t)B_ * H_ * S_ * HD_;   // 4,194,304
    float* Qw   = ws;
    float* Kw   = Qw + nqkv;
    float* Vw   = Kw + nqkv;
    float* cosT = Vw + nqkv;
    float* sinT = cosT + (size_t)S_ * 32;

    rope_table_kernel<<<dim3((S_ * 32 + 255) / 256), dim3(256), 0, stream>>>(cosT, sinT);
    qkv_gemm_kernel<<<dim3(24, 32), dim3(256), 0, stream>>>(X, Wq, Wk, Wv, bq, bk, bv,
                                                            cosT, sinT, Qw, Kw, Vw);
    attn_kernel<<<dim3(B_ * H_, S_ / 64), dim3(256), 0, stream>>>(Qw, Kw, Vw, am, out);
}

// Round 7
// 467.054 us; speedup vs baseline: 4.4277x; 4.4277x over previous
//
#include <hip/hip_runtime.h>
#include <hip/hip_bf16.h>
#include <math.h>

#define B_   2
#define S_   2048
#define D_   1024
#define H_   16
#define HD_  64
#define WIN_ 256

typedef __attribute__((ext_vector_type(8))) short bf16x8;
typedef __attribute__((ext_vector_type(4))) float f32x4;
typedef __attribute__((ext_vector_type(8))) unsigned short ushort8;

// ---------------------------------------------------------------------------
// RoPE cos/sin table: [S][32] each. Angle computed with f32 rounding (matches
// jnp f32 outer product), trig evaluated in f64 for accuracy.
// ---------------------------------------------------------------------------
__global__ void rope_table_kernel(float* __restrict__ cosT, float* __restrict__ sinT)
{
    int idx = blockIdx.x * 256 + threadIdx.x;
    if (idx >= S_ * 32) return;
    int s = idx >> 5;
    int i = idx & 31;
    float invf = 1.0f / powf(10000.0f, (float)(2 * i) / 64.0f);
    float ang  = (float)s * invf;                 // f32 rounding like reference
    double a = (double)ang;
    cosT[idx] = (float)cos(a);
    sinT[idx] = (float)sin(a);
}

// ---------------------------------------------------------------------------
// f32 -> (bf16 hi, bf16 lo): hi = bf16(x) RNE, lo = bf16(x - f32(hi)).
// Combined error ~2^-18 relative -> scores good to ~1e-3 absolute.
// ---------------------------------------------------------------------------
__device__ inline void split1(float x, ushort& h, ushort& l)
{
    __hip_bfloat16 hb = __float2bfloat16(x);
    float hf = __bfloat162float(hb);
    __hip_bfloat16 lb = __float2bfloat16(x - hf);
    h = *reinterpret_cast<ushort*>(&hb);
    l = *reinterpret_cast<ushort*>(&lb);
}

__device__ inline void split8(float4 f0, float4 f1, ushort8& hv, ushort8& lv)
{
    ushort h, l;
    split1(f0.x, h, l); hv[0] = h; lv[0] = l;
    split1(f0.y, h, l); hv[1] = h; lv[1] = l;
    split1(f0.z, h, l); hv[2] = h; lv[2] = l;
    split1(f0.w, h, l); hv[3] = h; lv[3] = l;
    split1(f1.x, h, l); hv[4] = h; lv[4] = l;
    split1(f1.y, h, l); hv[5] = h; lv[5] = l;
    split1(f1.z, h, l); hv[6] = h; lv[6] = l;
    split1(f1.w, h, l); hv[7] = h; lv[7] = l;
}

// ---------------------------------------------------------------------------
// QKV projection via split-bf16 MFMA: Y = X @ W^T + b, then RoPE for Q,K.
// The f32->bf16(hi,lo) split happens ON THE FLY in the staging loop (no
// extra pass, no extra workspace; f32 reads = hi+lo bf16 bytes anyway).
// acc = hi*hi + hi*lo + lo*hi  (three mfma_f32_16x16x32_bf16 per tile-pair).
// Tile 128x128, BK=32, 4 waves in 2x2, each wave 64x64 (4x4 MFMA tiles).
// Fragment layout (m89-verified): A row=lane&15, k=(lane>>4)*8+j;
// B col=lane&15, k=(lane>>4)*8+j; D col=lane&15, row=(lane>>4)*4+reg.
// LDS rows padded to 40 shorts (80 B): bank step 20 -> 2-way (free).
// Epilogue fuses bias + RoPE (pair d<->d+-32 is nt<->nt^2, same lane) and
// scatters to [B,H,S,64].
// ---------------------------------------------------------------------------
__global__ __launch_bounds__(256)
void qkv_mfma_kernel(const float* __restrict__ X,
                     const float* __restrict__ Wq, const float* __restrict__ Wk,
                     const float* __restrict__ Wv,
                     const float* __restrict__ bq, const float* __restrict__ bk,
                     const float* __restrict__ bv,
                     const float* __restrict__ cosT, const float* __restrict__ sinT,
                     float* __restrict__ Qo, float* __restrict__ Ko, float* __restrict__ Vo)
{
    __shared__ ushort Ah[128 * 40], Al[128 * 40], Bh[128 * 40], Bl[128 * 40];

    const int tid  = threadIdx.x;
    const int m0   = blockIdx.y * 128;
    const int nc0  = blockIdx.x * 128;
    const int wsel = nc0 >> 10;
    const int n_in0 = nc0 & 1023;

    const float* W  = (wsel == 0) ? Wq : (wsel == 1) ? Wk : Wv;
    const float* bi = (wsel == 0) ? bq : (wsel == 1) ? bk : bv;
    float* Out      = (wsel == 0) ? Qo : (wsel == 1) ? Ko : Vo;

    const int lane = tid & 63;
    const int w    = tid >> 6;
    const int wm = w >> 1, wn = w & 1;
    const int l15 = lane & 15, lk8 = lane >> 4;

    f32x4 acc[4][4];
#pragma unroll
    for (int mt = 0; mt < 4; ++mt)
#pragma unroll
        for (int nt = 0; nt < 4; ++nt)
            acc[mt][nt] = (f32x4){0.f, 0.f, 0.f, 0.f};

    const int srow = tid >> 2;   // 0..63
    const int sgc  = tid & 3;    // 0..3 (granule of 8 floats / 8 shorts)

    for (int k0 = 0; k0 < D_; k0 += 32) {
        __syncthreads();
#pragma unroll
        for (int rh = 0; rh < 2; ++rh) {
            const int row = srow + rh * 64;
            const size_t gA = (size_t)(m0 + row) * 1024 + k0 + sgc * 8;
            const size_t gB = (size_t)(n_in0 + row) * 1024 + k0 + sgc * 8;
            const int la = row * 40 + sgc * 8;
            float4 a0 = *(const float4*)&X[gA];
            float4 a1 = *(const float4*)&X[gA + 4];
            float4 b0 = *(const float4*)&W[gB];
            float4 b1 = *(const float4*)&W[gB + 4];
            ushort8 hv, lv;
            split8(a0, a1, hv, lv);
            *(ushort8*)&Ah[la] = hv;
            *(ushort8*)&Al[la] = lv;
            split8(b0, b1, hv, lv);
            *(ushort8*)&Bh[la] = hv;
            *(ushort8*)&Bl[la] = lv;
        }
        __syncthreads();

        bf16x8 ah[4], al[4], bh[4], bl[4];
#pragma unroll
        for (int mt = 0; mt < 4; ++mt) {
            const int idx = (wm * 64 + mt * 16 + l15) * 40 + lk8 * 8;
            ah[mt] = *(const bf16x8*)&Ah[idx];
            al[mt] = *(const bf16x8*)&Al[idx];
        }
#pragma unroll
        for (int nt = 0; nt < 4; ++nt) {
            const int idx = (wn * 64 + nt * 16 + l15) * 40 + lk8 * 8;
            bh[nt] = *(const bf16x8*)&Bh[idx];
            bl[nt] = *(const bf16x8*)&Bl[idx];
        }
#pragma unroll
        for (int mt = 0; mt < 4; ++mt)
#pragma unroll
            for (int nt = 0; nt < 4; ++nt) {
                acc[mt][nt] = __builtin_amdgcn_mfma_f32_16x16x32_bf16(ah[mt], bh[nt], acc[mt][nt], 0, 0, 0);
                acc[mt][nt] = __builtin_amdgcn_mfma_f32_16x16x32_bf16(ah[mt], bl[nt], acc[mt][nt], 0, 0, 0);
                acc[mt][nt] = __builtin_amdgcn_mfma_f32_16x16x32_bf16(al[mt], bh[nt], acc[mt][nt], 0, 0, 0);
            }
    }

    // ---- epilogue: bias, RoPE (Q,K only), scatter to [B,H,S,64] ----
    const int  b      = m0 >> 11;
    const bool doRope = (wsel < 2);
    const int  h      = (n_in0 + wn * 64) >> 6;   // constant per wave

    const float bias0 = bi[n_in0 + wn * 64 +  0 + l15];
    const float bias1 = bi[n_in0 + wn * 64 + 16 + l15];
    const float bias2 = bi[n_in0 + wn * 64 + 32 + l15];
    const float bias3 = bi[n_in0 + wn * 64 + 48 + l15];

#pragma unroll
    for (int mt = 0; mt < 4; ++mt)
#pragma unroll
        for (int r = 0; r < 4; ++r) {
            const int s = (m0 + wm * 64 + mt * 16 + lk8 * 4 + r) & (S_ - 1);
            float v0 = acc[mt][0][r] + bias0;
            float v1 = acc[mt][1][r] + bias1;
            float v2 = acc[mt][2][r] + bias2;
            float v3 = acc[mt][3][r] + bias3;
            float y0 = v0, y1 = v1, y2 = v2, y3 = v3;
            if (doRope) {
                const float c0 = cosT[s * 32 + l15];
                const float c1 = cosT[s * 32 + 16 + l15];
                const float s0 = sinT[s * 32 + l15];
                const float s1 = sinT[s * 32 + 16 + l15];
                y0 = v0 * c0 - v2 * s0;     // d in [0,16)
                y1 = v1 * c1 - v3 * s1;     // d in [16,32)
                y2 = v2 * c0 + v0 * s0;     // d in [32,48)
                y3 = v3 * c1 + v1 * s1;     // d in [48,64)
            }
            const size_t base = (((size_t)b * H_ + h) * S_ + s) * HD_;
            Out[base +  0 + l15] = y0;
            Out[base + 16 + l15] = y1;
            Out[base + 32 + l15] = y2;
            Out[base + 48 + l15] = y3;
        }
}

// ---------------------------------------------------------------------------
// Sliding-window attention, flash-style online softmax.
// Block: one (b,h) x 64 query rows. 256 thr; thread (ty,tx) owns rows
// ty*4+i and INTERLEAVED key cols j = tx + 16*c (c=0..3 -> .x...w).
// ALL per-thread state is named float4/float scalars (no indexable arrays ->
// nothing the compiler can demote to scratch; R2's 5.9 GB scratch regression).
// ---------------------------------------------------------------------------
#define DOT4(ACC, Q, K) \
    ACC = fmaf((Q).x, (K).x, fmaf((Q).y, (K).y, fmaf((Q).z, (K).z, fmaf((Q).w, (K).w, ACC))))

#define QK_ROW(SROW, RIDX) { \
    float4 q = *(const float4*)&Qs[ty * 4 + RIDX][d4 * 4]; \
    DOT4(SROW.x, q, k0); DOT4(SROW.y, q, k1); \
    DOT4(SROW.z, q, k2); DOT4(SROW.w, q, k3); }

#define SM_ROW(SROW, M, L, OROW, RIDX) { \
    const int qrow = i0 + ty * 4 + RIDX; \
    SROW.x = kx0 ? SROW.x : -3.0e38f; \
    SROW.y = kx1 ? SROW.y : -3.0e38f; \
    SROW.z = kx2 ? SROW.z : -3.0e38f; \
    SROW.w = kx3 ? SROW.w : -3.0e38f; \
    if (!fullTile) { \
        SROW.x = (jj0      >= qrow - WIN_ && jj0      <= qrow + WIN_) ? SROW.x : -3.0e38f; \
        SROW.y = (jj0 + 16 >= qrow - WIN_ && jj0 + 16 <= qrow + WIN_) ? SROW.y : -3.0e38f; \
        SROW.z = (jj0 + 32 >= qrow - WIN_ && jj0 + 32 <= qrow + WIN_) ? SROW.z : -3.0e38f; \
        SROW.w = (jj0 + 48 >= qrow - WIN_ && jj0 + 48 <= qrow + WIN_) ? SROW.w : -3.0e38f; \
    } \
    float rowm = fmaxf(fmaxf(SROW.x, SROW.y), fmaxf(SROW.z, SROW.w)); \
    rowm = fmaxf(rowm, __shfl_xor(rowm, 8, 64)); \
    rowm = fmaxf(rowm, __shfl_xor(rowm, 4, 64)); \
    rowm = fmaxf(rowm, __shfl_xor(rowm, 2, 64)); \
    rowm = fmaxf(rowm, __shfl_xor(rowm, 1, 64)); \
    const float mnew = fmaxf(M, rowm); \
    const float corr = __expf(M - mnew); \
    SROW.x = (SROW.x > -1.0e37f) ? __expf(SROW.x - mnew) : 0.f; \
    SROW.y = (SROW.y > -1.0e37f) ? __expf(SROW.y - mnew) : 0.f; \
    SROW.z = (SROW.z > -1.0e37f) ? __expf(SROW.z - mnew) : 0.f; \
    SROW.w = (SROW.w > -1.0e37f) ? __expf(SROW.w - mnew) : 0.f; \
    float rs = (SROW.x + SROW.y) + (SROW.z + SROW.w); \
    rs += __shfl_xor(rs, 8, 64); \
    rs += __shfl_xor(rs, 4, 64); \
    rs += __shfl_xor(rs, 2, 64); \
    rs += __shfl_xor(rs, 1, 64); \
    L = L * corr + rs; M = mnew; \
    OROW.x *= corr; OROW.y *= corr; OROW.z *= corr; OROW.w *= corr; }

#define PV_ROW(OROW, RIDX) { \
    float4 p = *(const float4*)&Ks[ty * 4 + RIDX][c4 * 4]; \
    OROW.x = fmaf(p.x, v0.x, fmaf(p.y, v1.x, fmaf(p.z, v2.x, fmaf(p.w, v3.x, OROW.x)))); \
    OROW.y = fmaf(p.x, v0.y, fmaf(p.y, v1.y, fmaf(p.z, v2.y, fmaf(p.w, v3.y, OROW.y)))); \
    OROW.z = fmaf(p.x, v0.z, fmaf(p.y, v1.z, fmaf(p.z, v2.z, fmaf(p.w, v3.z, OROW.z)))); \
    OROW.w = fmaf(p.x, v0.w, fmaf(p.y, v1.w, fmaf(p.z, v2.w, fmaf(p.w, v3.w, OROW.w)))); }

#define OUT_ROW(OROW, M, L, RIDX) { \
    const int qrow = i0 + ty * 4 + RIDX; \
    const float rl = (L > 0.f) ? (1.0f / L) : 0.f; \
    const float qm = (amask[b * S_ + qrow] > 0) ? 1.f : 0.f; \
    const float f = rl * qm; \
    float4 v; \
    v.x = OROW.x * f; v.y = OROW.y * f; v.z = OROW.z * f; v.w = OROW.w * f; \
    *(float4*)&out[((size_t)b * S_ + qrow) * D_ + h * HD_ + tx * 4] = v; }

__global__ __launch_bounds__(256)
void attn_kernel(const float* __restrict__ Q, const float* __restrict__ K,
                 const float* __restrict__ V, const int* __restrict__ amask,
                 float* __restrict__ out)
{
    __shared__ float Qs[64][68];
    __shared__ float Ks[64][68];   // K tile, then P tile
    __shared__ float Vs[64][68];

    const int tid = threadIdx.x;
    const int ty = tid >> 4, tx = tid & 15;
    const int bh = blockIdx.x;
    const int b  = bh >> 4;
    const int i0 = blockIdx.y * 64;

    const float* Qb = Q + (size_t)bh * S_ * HD_;
    const float* Kb = K + (size_t)bh * S_ * HD_;
    const float* Vb = V + (size_t)bh * S_ * HD_;

#pragma unroll
    for (int r = 0; r < 4; ++r) {
        const int qi = tid + r * 256;
        const int row = qi >> 4, q4 = qi & 15;
        float4 qv = *(const float4*)&Qb[(size_t)(i0 + row) * HD_ + q4 * 4];
        qv.x *= 8.f; qv.y *= 8.f; qv.z *= 8.f; qv.w *= 8.f;   // fold score scale
        *(float4*)&Qs[row][q4 * 4] = qv;
    }

    float4 O0 = {0.f,0.f,0.f,0.f}, O1 = O0, O2 = O0, O3 = O0;
    float mA = -3.0e38f, mB = -3.0e38f, mC = -3.0e38f, mD = -3.0e38f;
    float lA = 0.f, lB = 0.f, lC = 0.f, lD = 0.f;

    const int jlo   = (i0 - WIN_ > 0) ? (i0 - WIN_) : 0;
    const int jhiex = (i0 + 64 + WIN_ < S_) ? (i0 + 64 + WIN_) : S_;

    for (int jt = jlo; jt < jhiex; jt += 64) {
        __syncthreads();
#pragma unroll
        for (int r = 0; r < 4; ++r) {
            const int qi = tid + r * 256;
            const int row = qi >> 4, q4 = qi & 15;
            *(float4*)&Ks[row][q4 * 4] = *(const float4*)&Kb[(size_t)(jt + row) * HD_ + q4 * 4];
            *(float4*)&Vs[row][q4 * 4] = *(const float4*)&Vb[(size_t)(jt + row) * HD_ + q4 * 4];
        }
        __syncthreads();

        // ---- S = Q @ K^T (interleaved cols: .x->tx, .y->tx+16, ...) ----
        float4 s0 = {0.f,0.f,0.f,0.f}, s1 = s0, s2 = s0, s3 = s0;
#pragma unroll
        for (int d4 = 0; d4 < 16; ++d4) {
            float4 k0 = *(const float4*)&Ks[tx +  0][d4 * 4];
            float4 k1 = *(const float4*)&Ks[tx + 16][d4 * 4];
            float4 k2 = *(const float4*)&Ks[tx + 32][d4 * 4];
            float4 k3 = *(const float4*)&Ks[tx + 48][d4 * 4];
            QK_ROW(s0, 0) QK_ROW(s1, 1) QK_ROW(s2, 2) QK_ROW(s3, 3)
        }

        // ---- online softmax (s* becomes P in place) ----
        const bool fullTile = (jt - i0 >= -192) && (jt - i0 <= 192);
        const int jj0 = jt + tx;
        const bool kx0 = (amask[b * S_ + jj0 +  0] > 0);
        const bool kx1 = (amask[b * S_ + jj0 + 16] > 0);
        const bool kx2 = (amask[b * S_ + jj0 + 32] > 0);
        const bool kx3 = (amask[b * S_ + jj0 + 48] > 0);

        SM_ROW(s0, mA, lA, O0, 0)
        SM_ROW(s1, mB, lB, O1, 1)
        SM_ROW(s2, mC, lC, O2, 2)
        SM_ROW(s3, mD, lD, O3, 3)

        __syncthreads();   // K reads done; Ks becomes P
        Ks[ty * 4 + 0][tx] = s0.x; Ks[ty * 4 + 0][tx + 16] = s0.y;
        Ks[ty * 4 + 0][tx + 32] = s0.z; Ks[ty * 4 + 0][tx + 48] = s0.w;
        Ks[ty * 4 + 1][tx] = s1.x; Ks[ty * 4 + 1][tx + 16] = s1.y;
        Ks[ty * 4 + 1][tx + 32] = s1.z; Ks[ty * 4 + 1][tx + 48] = s1.w;
        Ks[ty * 4 + 2][tx] = s2.x; Ks[ty * 4 + 2][tx + 16] = s2.y;
        Ks[ty * 4 + 2][tx + 32] = s2.z; Ks[ty * 4 + 2][tx + 48] = s2.w;
        Ks[ty * 4 + 3][tx] = s3.x; Ks[ty * 4 + 3][tx + 16] = s3.y;
        Ks[ty * 4 + 3][tx + 32] = s3.z; Ks[ty * 4 + 3][tx + 48] = s3.w;
        __syncthreads();

        // ---- O += P @ V ----
#pragma unroll
        for (int c4 = 0; c4 < 16; ++c4) {
            float4 v0 = *(const float4*)&Vs[c4 * 4 + 0][tx * 4];
            float4 v1 = *(const float4*)&Vs[c4 * 4 + 1][tx * 4];
            float4 v2 = *(const float4*)&Vs[c4 * 4 + 2][tx * 4];
            float4 v3 = *(const float4*)&Vs[c4 * 4 + 3][tx * 4];
            PV_ROW(O0, 0) PV_ROW(O1, 1) PV_ROW(O2, 2) PV_ROW(O3, 3)
        }
    }

    // ---- epilogue: normalize, query-mask, write [B,S,D] ----
    const int h = bh & 15;
    OUT_ROW(O0, mA, lA, 0)
    OUT_ROW(O1, mB, lB, 1)
    OUT_ROW(O2, mC, lC, 2)
    OUT_ROW(O3, mD, lD, 3)
}

// ---------------------------------------------------------------------------
extern "C" void kernel_launch(void* const* d_in, const int* in_sizes, int n_in,
                              void* d_out, int out_size, void* d_ws, size_t ws_size,
                              hipStream_t stream)
{
    const float* X  = (const float*)d_in[0];
    const int*   am = (const int*)d_in[1];
    const float* Wq = (const float*)d_in[2];
    const float* bq = (const float*)d_in[3];
    const float* Wk = (const float*)d_in[4];
    const float* bk = (const float*)d_in[5];
    const float* Wv = (const float*)d_in[6];
    const float* bv = (const float*)d_in[7];
    float* out = (float*)d_out;

    float* ws = (float*)d_ws;
    const size_t nqkv = (size_t)B_ * H_ * S_ * HD_;   // 4,194,304
    float* Qw   = ws;
    float* Kw   = Qw + nqkv;
    float* Vw   = Kw + nqkv;
    float* cosT = Vw + nqkv;
    float* sinT = cosT + (size_t)S_ * 32;

    rope_table_kernel<<<dim3((S_ * 32 + 255) / 256), dim3(256), 0, stream>>>(cosT, sinT);
    qkv_mfma_kernel<<<dim3(24, 32), dim3(256), 0, stream>>>(
        X, Wq, Wk, Wv, bq, bk, bv, cosT, sinT, Qw, Kw, Vw);
    attn_kernel<<<dim3(B_ * H_, S_ / 64), dim3(256), 0, stream>>>(Qw, Kw, Vw, am, out);
}

// Round 8
// 265.024 us; speedup vs baseline: 7.8029x; 1.7623x over previous
//
#include <hip/hip_runtime.h>
#include <hip/hip_bf16.h>
#include <math.h>

#define B_   2
#define S_   2048
#define D_   1024
#define H_   16
#define HD_  64
#define WIN_ 256

typedef __attribute__((ext_vector_type(8))) short bf16x8;
typedef __attribute__((ext_vector_type(4))) float f32x4;
typedef __attribute__((ext_vector_type(8))) unsigned short ushort8;

// ---------------------------------------------------------------------------
// RoPE cos/sin table: [S][32] each. f32 angle rounding (matches jnp), f64 trig.
// ---------------------------------------------------------------------------
__global__ void rope_table_kernel(float* __restrict__ cosT, float* __restrict__ sinT)
{
    int idx = blockIdx.x * 256 + threadIdx.x;
    if (idx >= S_ * 32) return;
    int s = idx >> 5;
    int i = idx & 31;
    float invf = 1.0f / powf(10000.0f, (float)(2 * i) / 64.0f);
    float ang  = (float)s * invf;
    double a = (double)ang;
    cosT[idx] = (float)cos(a);
    sinT[idx] = (float)sin(a);
}

// ---------------------------------------------------------------------------
// f32 -> (bf16 hi, bf16 lo): hi = bf16(x) RNE, lo = bf16(x - f32(hi)).
// ---------------------------------------------------------------------------
__device__ inline void split1(float x, ushort& h, ushort& l)
{
    __hip_bfloat16 hb = __float2bfloat16(x);
    float hf = __bfloat162float(hb);
    __hip_bfloat16 lb = __float2bfloat16(x - hf);
    h = *reinterpret_cast<ushort*>(&hb);
    l = *reinterpret_cast<ushort*>(&lb);
}

__device__ inline void split8(float4 f0, float4 f1, ushort8& hv, ushort8& lv)
{
    ushort h, l;
    split1(f0.x, h, l); hv[0] = h; lv[0] = l;
    split1(f0.y, h, l); hv[1] = h; lv[1] = l;
    split1(f0.z, h, l); hv[2] = h; lv[2] = l;
    split1(f0.w, h, l); hv[3] = h; lv[3] = l;
    split1(f1.x, h, l); hv[4] = h; lv[4] = l;
    split1(f1.y, h, l); hv[5] = h; lv[5] = l;
    split1(f1.z, h, l); hv[6] = h; lv[6] = l;
    split1(f1.w, h, l); hv[7] = h; lv[7] = l;
}

__device__ inline ushort bfu(float x)
{
    __hip_bfloat16 t = __float2bfloat16(x);
    return *reinterpret_cast<ushort*>(&t);
}

// ---------------------------------------------------------------------------
// QKV projection via split-bf16 MFMA (UNCHANGED from R7 — measured ~150us,
// passed absmax 0.015625). Tile 128x128, BK=32, on-the-fly hi/lo split,
// fused bias + RoPE epilogue, scatter to [B,H,S,64].
// ---------------------------------------------------------------------------
__global__ __launch_bounds__(256)
void qkv_mfma_kernel(const float* __restrict__ X,
                     const float* __restrict__ Wq, const float* __restrict__ Wk,
                     const float* __restrict__ Wv,
                     const float* __restrict__ bq, const float* __restrict__ bk,
                     const float* __restrict__ bv,
                     const float* __restrict__ cosT, const float* __restrict__ sinT,
                     float* __restrict__ Qo, float* __restrict__ Ko, float* __restrict__ Vo)
{
    __shared__ ushort Ah[128 * 40], Al[128 * 40], Bh[128 * 40], Bl[128 * 40];

    const int tid  = threadIdx.x;
    const int m0   = blockIdx.y * 128;
    const int nc0  = blockIdx.x * 128;
    const int wsel = nc0 >> 10;
    const int n_in0 = nc0 & 1023;

    const float* W  = (wsel == 0) ? Wq : (wsel == 1) ? Wk : Wv;
    const float* bi = (wsel == 0) ? bq : (wsel == 1) ? bk : bv;
    float* Out      = (wsel == 0) ? Qo : (wsel == 1) ? Ko : Vo;

    const int lane = tid & 63;
    const int w    = tid >> 6;
    const int wm = w >> 1, wn = w & 1;
    const int l15 = lane & 15, lk8 = lane >> 4;

    f32x4 acc[4][4];
#pragma unroll
    for (int mt = 0; mt < 4; ++mt)
#pragma unroll
        for (int nt = 0; nt < 4; ++nt)
            acc[mt][nt] = (f32x4){0.f, 0.f, 0.f, 0.f};

    const int srow = tid >> 2;
    const int sgc  = tid & 3;

    for (int k0 = 0; k0 < D_; k0 += 32) {
        __syncthreads();
#pragma unroll
        for (int rh = 0; rh < 2; ++rh) {
            const int row = srow + rh * 64;
            const size_t gA = (size_t)(m0 + row) * 1024 + k0 + sgc * 8;
            const size_t gB = (size_t)(n_in0 + row) * 1024 + k0 + sgc * 8;
            const int la = row * 40 + sgc * 8;
            float4 a0 = *(const float4*)&X[gA];
            float4 a1 = *(const float4*)&X[gA + 4];
            float4 b0 = *(const float4*)&W[gB];
            float4 b1 = *(const float4*)&W[gB + 4];
            ushort8 hv, lv;
            split8(a0, a1, hv, lv);
            *(ushort8*)&Ah[la] = hv;
            *(ushort8*)&Al[la] = lv;
            split8(b0, b1, hv, lv);
            *(ushort8*)&Bh[la] = hv;
            *(ushort8*)&Bl[la] = lv;
        }
        __syncthreads();

        bf16x8 ah[4], al[4], bh[4], bl[4];
#pragma unroll
        for (int mt = 0; mt < 4; ++mt) {
            const int idx = (wm * 64 + mt * 16 + l15) * 40 + lk8 * 8;
            ah[mt] = *(const bf16x8*)&Ah[idx];
            al[mt] = *(const bf16x8*)&Al[idx];
        }
#pragma unroll
        for (int nt = 0; nt < 4; ++nt) {
            const int idx = (wn * 64 + nt * 16 + l15) * 40 + lk8 * 8;
            bh[nt] = *(const bf16x8*)&Bh[idx];
            bl[nt] = *(const bf16x8*)&Bl[idx];
        }
#pragma unroll
        for (int mt = 0; mt < 4; ++mt)
#pragma unroll
            for (int nt = 0; nt < 4; ++nt) {
                acc[mt][nt] = __builtin_amdgcn_mfma_f32_16x16x32_bf16(ah[mt], bh[nt], acc[mt][nt], 0, 0, 0);
                acc[mt][nt] = __builtin_amdgcn_mfma_f32_16x16x32_bf16(ah[mt], bl[nt], acc[mt][nt], 0, 0, 0);
                acc[mt][nt] = __builtin_amdgcn_mfma_f32_16x16x32_bf16(al[mt], bh[nt], acc[mt][nt], 0, 0, 0);
            }
    }

    const int  b      = m0 >> 11;
    const bool doRope = (wsel < 2);
    const int  h      = (n_in0 + wn * 64) >> 6;

    const float bias0 = bi[n_in0 + wn * 64 +  0 + l15];
    const float bias1 = bi[n_in0 + wn * 64 + 16 + l15];
    const float bias2 = bi[n_in0 + wn * 64 + 32 + l15];
    const float bias3 = bi[n_in0 + wn * 64 + 48 + l15];

#pragma unroll
    for (int mt = 0; mt < 4; ++mt)
#pragma unroll
        for (int r = 0; r < 4; ++r) {
            const int s = (m0 + wm * 64 + mt * 16 + lk8 * 4 + r) & (S_ - 1);
            float v0 = acc[mt][0][r] + bias0;
            float v1 = acc[mt][1][r] + bias1;
            float v2 = acc[mt][2][r] + bias2;
            float v3 = acc[mt][3][r] + bias3;
            float y0 = v0, y1 = v1, y2 = v2, y3 = v3;
            if (doRope) {
                const float c0 = cosT[s * 32 + l15];
                const float c1 = cosT[s * 32 + 16 + l15];
                const float s0 = sinT[s * 32 + l15];
                const float s1 = sinT[s * 32 + 16 + l15];
                y0 = v0 * c0 - v2 * s0;
                y1 = v1 * c1 - v3 * s1;
                y2 = v2 * c0 + v0 * s0;
                y3 = v3 * c1 + v1 * s1;
            }
            const size_t base = (((size_t)b * H_ + h) * S_ + s) * HD_;
            Out[base +  0 + l15] = y0;
            Out[base + 16 + l15] = y1;
            Out[base + 32 + l15] = y2;
            Out[base + 48 + l15] = y3;
        }
}

// ---------------------------------------------------------------------------
// Sliding-window attention via split-bf16 MFMA.
// Block = one (b,h) x 64 q-rows, 4 waves; wave w owns q-rows [w*16, w*16+16).
// Q: registers (A-frag hi/lo, x8 scale folded, exact).
// K: LDS [key][d] pitch 72 (hi+lo).  V: LDS TRANSPOSED [d][key] pitch 72
// (hi+lo, packed u32 writes).  P: own LDS buffer, bf16, wave-private stripe
// (written in D-layout positions, read back in A-frag layout).
// QK^T = qh*kh + qh*kl + ql*kh (score err ~2^-18, same as GEMM, HW-validated
// at absmax 0.015625).  PV = p*(vh) + p*(vl)  (P bf16: ~0.2% rel).
// Softmax per D-fragment row: in-reg max over 4 nt + shfl_xor{1,2,4,8}
// within the 16-lane column group.
// LDS total: 5 x 64*72*2B = 46080 B -> 3 blocks/CU (LDS-bound).
// ---------------------------------------------------------------------------
__global__ __launch_bounds__(256)
void attn_mfma_kernel(const float* __restrict__ Q, const float* __restrict__ K,
                      const float* __restrict__ V, const int* __restrict__ amask,
                      float* __restrict__ out)
{
    __shared__ ushort Kh[64 * 72], Kl[64 * 72];
    __shared__ ushort Vth[64 * 72], Vtl[64 * 72];
    __shared__ ushort Ps[64 * 72];

    const int tid  = threadIdx.x;
    const int lane = tid & 63;
    const int w    = tid >> 6;
    const int l15  = lane & 15, lk8 = lane >> 4;
    const int bh   = blockIdx.x;
    const int b    = bh >> 4;
    const int h    = bh & 15;
    const int i0   = blockIdx.y * 64;

    const float* Qb = Q + (size_t)bh * S_ * HD_;
    const float* Kb = K + (size_t)bh * S_ * HD_;
    const float* Vb = V + (size_t)bh * S_ * HD_;

    // ---- Q A-fragments in registers (scaled by 8 = exact pow2) ----
    bf16x8 qh0, ql0, qh1, ql1;
    {
        const int qrow = i0 + w * 16 + l15;
        const float* qp = &Qb[(size_t)qrow * HD_];
        float4 f0 = *(const float4*)(qp + lk8 * 8);
        float4 f1 = *(const float4*)(qp + lk8 * 8 + 4);
        f0.x *= 8.f; f0.y *= 8.f; f0.z *= 8.f; f0.w *= 8.f;
        f1.x *= 8.f; f1.y *= 8.f; f1.z *= 8.f; f1.w *= 8.f;
        ushort8 hv, lv;
        split8(f0, f1, hv, lv);
        qh0 = *(bf16x8*)&hv; ql0 = *(bf16x8*)&lv;
        f0 = *(const float4*)(qp + 32 + lk8 * 8);
        f1 = *(const float4*)(qp + 32 + lk8 * 8 + 4);
        f0.x *= 8.f; f0.y *= 8.f; f0.z *= 8.f; f0.w *= 8.f;
        f1.x *= 8.f; f1.y *= 8.f; f1.z *= 8.f; f1.w *= 8.f;
        split8(f0, f1, hv, lv);
        qh1 = *(bf16x8*)&hv; ql1 = *(bf16x8*)&lv;
    }

    f32x4 O_[4];
#pragma unroll
    for (int nt = 0; nt < 4; ++nt) O_[nt] = (f32x4){0.f, 0.f, 0.f, 0.f};
    float mrow[4] = {-3.0e38f, -3.0e38f, -3.0e38f, -3.0e38f};
    float lrow[4] = {0.f, 0.f, 0.f, 0.f};

    const int jlo   = (i0 - WIN_ > 0) ? (i0 - WIN_) : 0;
    const int jhiex = (i0 + 64 + WIN_ < S_) ? (i0 + 64 + WIN_) : S_;

    // staging coords
    const int skey = tid >> 2;              // K: 0..63
    const int sd0  = (tid & 3) * 16;        // K: d 0,16,32,48
    const int vk0  = (tid & 31) * 2;        // V: key pair
    const int vd0  = (tid >> 5) * 8;        // V: d group 0..56

    for (int jt = jlo; jt < jhiex; jt += 64) {
        __syncthreads();   // prev tile's PV reads of Vt/K done

        // ---- stage K [key][d] (hi/lo) ----
        {
            const float* kp = &Kb[(size_t)(jt + skey) * HD_ + sd0];
            float4 f0 = *(const float4*)kp;
            float4 f1 = *(const float4*)(kp + 4);
            float4 f2 = *(const float4*)(kp + 8);
            float4 f3 = *(const float4*)(kp + 12);
            ushort8 hv, lv;
            split8(f0, f1, hv, lv);
            *(ushort8*)&Kh[skey * 72 + sd0] = hv;
            *(ushort8*)&Kl[skey * 72 + sd0] = lv;
            split8(f2, f3, hv, lv);
            *(ushort8*)&Kh[skey * 72 + sd0 + 8] = hv;
            *(ushort8*)&Kl[skey * 72 + sd0 + 8] = lv;
        }
        // ---- stage V transposed [d][key] (hi/lo), packed u32 writes ----
        {
            const float* va = &Vb[(size_t)(jt + vk0) * HD_ + vd0];
            const float* vb = &Vb[(size_t)(jt + vk0 + 1) * HD_ + vd0];
            float4 a0 = *(const float4*)va;
            float4 a1 = *(const float4*)(va + 4);
            float4 b0 = *(const float4*)vb;
            float4 b1 = *(const float4*)(vb + 4);
            float av[8] = {a0.x, a0.y, a0.z, a0.w, a1.x, a1.y, a1.z, a1.w};
            float bv[8] = {b0.x, b0.y, b0.z, b0.w, b1.x, b1.y, b1.z, b1.w};
#pragma unroll
            for (int j = 0; j < 8; ++j) {
                ushort ha, la, hb2, lb2;
                split1(av[j], ha, la);
                split1(bv[j], hb2, lb2);
                *(unsigned int*)&Vth[(vd0 + j) * 72 + vk0] = (unsigned int)ha | ((unsigned int)hb2 << 16);
                *(unsigned int*)&Vtl[(vd0 + j) * 72 + vk0] = (unsigned int)la | ((unsigned int)lb2 << 16);
            }
        }
        __syncthreads();

        // ---- S = Q @ K^T  (3-term split-bf16 MFMA) ----
        f32x4 sacc[4];
#pragma unroll
        for (int nt = 0; nt < 4; ++nt) sacc[nt] = (f32x4){0.f, 0.f, 0.f, 0.f};
        {
            bf16x8 kh_[4], kl_[4];
#pragma unroll
            for (int nt = 0; nt < 4; ++nt) {
                const int a = (nt * 16 + l15) * 72 + lk8 * 8;
                kh_[nt] = *(const bf16x8*)&Kh[a];
                kl_[nt] = *(const bf16x8*)&Kl[a];
            }
#pragma unroll
            for (int nt = 0; nt < 4; ++nt) {
                sacc[nt] = __builtin_amdgcn_mfma_f32_16x16x32_bf16(qh0, kh_[nt], sacc[nt], 0, 0, 0);
                sacc[nt] = __builtin_amdgcn_mfma_f32_16x16x32_bf16(qh0, kl_[nt], sacc[nt], 0, 0, 0);
                sacc[nt] = __builtin_amdgcn_mfma_f32_16x16x32_bf16(ql0, kh_[nt], sacc[nt], 0, 0, 0);
            }
#pragma unroll
            for (int nt = 0; nt < 4; ++nt) {
                const int a = (nt * 16 + l15) * 72 + 32 + lk8 * 8;
                kh_[nt] = *(const bf16x8*)&Kh[a];
                kl_[nt] = *(const bf16x8*)&Kl[a];
            }
#pragma unroll
            for (int nt = 0; nt < 4; ++nt) {
                sacc[nt] = __builtin_amdgcn_mfma_f32_16x16x32_bf16(qh1, kh_[nt], sacc[nt], 0, 0, 0);
                sacc[nt] = __builtin_amdgcn_mfma_f32_16x16x32_bf16(qh1, kl_[nt], sacc[nt], 0, 0, 0);
                sacc[nt] = __builtin_amdgcn_mfma_f32_16x16x32_bf16(ql1, kh_[nt], sacc[nt], 0, 0, 0);
            }
        }

        // ---- online softmax on D fragments; write P (bf16) to own stripe ----
        const bool fullTile = (jt - i0 >= -192) && (jt - i0 <= 192);
        const int jj0 = jt + l15;
        const bool kx0 = (amask[b * S_ + jj0 +  0] > 0);
        const bool kx1 = (amask[b * S_ + jj0 + 16] > 0);
        const bool kx2 = (amask[b * S_ + jj0 + 32] > 0);
        const bool kx3 = (amask[b * S_ + jj0 + 48] > 0);

#pragma unroll
        for (int r = 0; r < 4; ++r) {
            const int qrow = i0 + w * 16 + lk8 * 4 + r;
            float sv0 = sacc[0][r], sv1 = sacc[1][r], sv2 = sacc[2][r], sv3 = sacc[3][r];
            sv0 = kx0 ? sv0 : -3.0e38f;
            sv1 = kx1 ? sv1 : -3.0e38f;
            sv2 = kx2 ? sv2 : -3.0e38f;
            sv3 = kx3 ? sv3 : -3.0e38f;
            if (!fullTile) {
                sv0 = (jj0      >= qrow - WIN_ && jj0      <= qrow + WIN_) ? sv0 : -3.0e38f;
                sv1 = (jj0 + 16 >= qrow - WIN_ && jj0 + 16 <= qrow + WIN_) ? sv1 : -3.0e38f;
                sv2 = (jj0 + 32 >= qrow - WIN_ && jj0 + 32 <= qrow + WIN_) ? sv2 : -3.0e38f;
                sv3 = (jj0 + 48 >= qrow - WIN_ && jj0 + 48 <= qrow + WIN_) ? sv3 : -3.0e38f;
            }
            float rowm = fmaxf(fmaxf(sv0, sv1), fmaxf(sv2, sv3));
            rowm = fmaxf(rowm, __shfl_xor(rowm, 1, 64));
            rowm = fmaxf(rowm, __shfl_xor(rowm, 2, 64));
            rowm = fmaxf(rowm, __shfl_xor(rowm, 4, 64));
            rowm = fmaxf(rowm, __shfl_xor(rowm, 8, 64));
            const float mnew = fmaxf(mrow[r], rowm);
            const float corr = __expf(mrow[r] - mnew);
            const float p0 = (sv0 > -1.0e37f) ? __expf(sv0 - mnew) : 0.f;
            const float p1 = (sv1 > -1.0e37f) ? __expf(sv1 - mnew) : 0.f;
            const float p2 = (sv2 > -1.0e37f) ? __expf(sv2 - mnew) : 0.f;
            const float p3 = (sv3 > -1.0e37f) ? __expf(sv3 - mnew) : 0.f;
            float rs = (p0 + p1) + (p2 + p3);
            rs += __shfl_xor(rs, 1, 64);
            rs += __shfl_xor(rs, 2, 64);
            rs += __shfl_xor(rs, 4, 64);
            rs += __shfl_xor(rs, 8, 64);
            lrow[r] = lrow[r] * corr + rs;
            mrow[r] = mnew;
            O_[0][r] *= corr; O_[1][r] *= corr; O_[2][r] *= corr; O_[3][r] *= corr;
            const int prow = (w * 16 + lk8 * 4 + r) * 72;
            Ps[prow +  0 + l15] = bfu(p0);
            Ps[prow + 16 + l15] = bfu(p1);
            Ps[prow + 32 + l15] = bfu(p2);
            Ps[prow + 48 + l15] = bfu(p3);
        }

        __syncthreads();   // P visible (wave-private stripes; kept for safety)

        // ---- O += P @ V  (P bf16 x V hi/lo) ----
#pragma unroll
        for (int ks = 0; ks < 2; ++ks) {
            const bf16x8 pa = *(const bf16x8*)&Ps[(w * 16 + l15) * 72 + ks * 32 + lk8 * 8];
#pragma unroll
            for (int nt = 0; nt < 4; ++nt) {
                const int a = (nt * 16 + l15) * 72 + ks * 32 + lk8 * 8;
                const bf16x8 vh = *(const bf16x8*)&Vth[a];
                const bf16x8 vl = *(const bf16x8*)&Vtl[a];
                O_[nt] = __builtin_amdgcn_mfma_f32_16x16x32_bf16(pa, vh, O_[nt], 0, 0, 0);
                O_[nt] = __builtin_amdgcn_mfma_f32_16x16x32_bf16(pa, vl, O_[nt], 0, 0, 0);
            }
        }
    }

    // ---- epilogue: normalize, query-mask, write [B,S,D] ----
#pragma unroll
    for (int r = 0; r < 4; ++r) {
        const int qrow = i0 + w * 16 + lk8 * 4 + r;
        const float rl = (lrow[r] > 0.f) ? (1.0f / lrow[r]) : 0.f;
        const float qm = (amask[b * S_ + qrow] > 0) ? 1.f : 0.f;
        const float f = rl * qm;
        const size_t base = ((size_t)b * S_ + qrow) * D_ + h * HD_;
        out[base +  0 + l15] = O_[0][r] * f;
        out[base + 16 + l15] = O_[1][r] * f;
        out[base + 32 + l15] = O_[2][r] * f;
        out[base + 48 + l15] = O_[3][r] * f;
    }
}

// ---------------------------------------------------------------------------
extern "C" void kernel_launch(void* const* d_in, const int* in_sizes, int n_in,
                              void* d_out, int out_size, void* d_ws, size_t ws_size,
                              hipStream_t stream)
{
    const float* X  = (const float*)d_in[0];
    const int*   am = (const int*)d_in[1];
    const float* Wq = (const float*)d_in[2];
    const float* bq = (const float*)d_in[3];
    const float* Wk = (const float*)d_in[4];
    const float* bk = (const float*)d_in[5];
    const float* Wv = (const float*)d_in[6];
    const float* bv = (const float*)d_in[7];
    float* out = (float*)d_out;

    float* ws = (float*)d_ws;
    const size_t nqkv = (size_t)B_ * H_ * S_ * HD_;   // 4,194,304
    float* Qw   = ws;
    float* Kw   = Qw + nqkv;
    float* Vw   = Kw + nqkv;
    float* cosT = Vw + nqkv;
    float* sinT = cosT + (size_t)S_ * 32;

    rope_table_kernel<<<dim3((S_ * 32 + 255) / 256), dim3(256), 0, stream>>>(cosT, sinT);
    qkv_mfma_kernel<<<dim3(24, 32), dim3(256), 0, stream>>>(
        X, Wq, Wk, Wv, bq, bk, bv, cosT, sinT, Qw, Kw, Vw);
    attn_mfma_kernel<<<dim3(B_ * H_, S_ / 64), dim3(256), 0, stream>>>(Qw, Kw, Vw, am, out);
}